// Round 3
// baseline (184.026 us; speedup 1.0000x reference)
//
#include <hip/hip_runtime.h>
#include <hip/hip_cooperative_groups.h>

namespace cg = cooperative_groups;

#define H_IMG 384
#define W_IMG 640
#define NPAIR 4
#define NBATCH 8
#define NBOX 100
#define DHID 256
#define ROWTILE 24
#define NTILES (H_IMG / ROWTILE)   // 16
#define NBLOCKS 256
#define NWAVES (NBLOCKS * 4)       // 1024 waves

// ---------------------------------------------------------------------------
// Single cooperative kernel, 3 phases separated by grid.sync():
//  P1: per-row channel-sum diff + fp32 row inclusive scan  -> sat
//  P2: in-place column scan within 24-row tiles, emit tile totals
//  P3 (blocks 0..7): LDS tile-offset table, SAT box scores, top-2
//      (jax tie-break), gather, fused Linear, interleaved output.
// ---------------------------------------------------------------------------
__global__ __launch_bounds__(256, 1) void k_fused(
        const float* __restrict__ images,
        float* __restrict__ sat,
        float* __restrict__ totals,
        const float* __restrict__ pred_boxes,
        const float* __restrict__ lhs,
        const float* __restrict__ fc_w,
        const float* __restrict__ fc_b,
        float* __restrict__ out) {
    cg::grid_group grid = cg::this_grid();
    const int t = threadIdx.x;
    const int lane = t & 63;
    const int wid = blockIdx.x * 4 + (t >> 6);

    // ---------------- Phase 1: diff + row scan ----------------
    const size_t chw = (size_t)H_IMG * W_IMG;
    for (int row = wid; row < NPAIR * H_IMG; row += NWAVES) {
        const int p = row / H_IMG;
        const int h = row - p * H_IMG;
        const float* i0 = images + ((size_t)(2 * p)     * 3 * H_IMG + h) * W_IMG;
        const float* i1 = images + ((size_t)(2 * p + 1) * 3 * H_IMG + h) * W_IMG;
        float* srow = sat + ((size_t)p * H_IMG + h) * W_IMG;

        float carry = 0.0f;
        #pragma unroll
        for (int k = 0; k < W_IMG / 64; ++k) {
            const int w = k * 64 + lane;
            float s0 = (i0[w] + i0[w + chw]) + i0[w + 2 * chw];
            float s1 = (i1[w] + i1[w + chw]) + i1[w + 2 * chw];
            float v = fabsf(s1 - s0);
            #pragma unroll
            for (int off = 1; off < 64; off <<= 1) {
                float u = __shfl_up(v, off, 64);
                if (lane >= off) v += u;
            }
            v += carry;
            srow[w] = v;
            carry = __shfl(v, 63, 64);
        }
    }
    grid.sync();

    // ---------------- Phase 2: local tile column scan ----------------
    for (int g = wid; g < NPAIR * 10 * NTILES; g += NWAVES) {
        const int p  = g / (10 * NTILES);
        const int r1 = g - p * (10 * NTILES);
        const int tt = r1 / 10;
        const int cg2 = r1 - tt * 10;
        const int c  = cg2 * 64 + lane;

        float* base = sat + ((size_t)p * H_IMG + tt * ROWTILE) * W_IMG + c;
        float run = 0.0f;
        #pragma unroll
        for (int i = 0; i < ROWTILE; ++i) {
            run += base[(size_t)i * W_IMG];
            base[(size_t)i * W_IMG] = run;
        }
        totals[((size_t)p * NTILES + tt) * W_IMG + c] = run;
    }
    grid.sync();

    // ---------------- Phase 3: score + top-2 + FC (blocks 0..7) ----------------
    __shared__ float s_off[NTILES][W_IMG];   // 40 KB
    __shared__ float s_score[NBOX];
    __shared__ int   s_idx[2];
    __shared__ float s_h[2][DHID];

    const int b = blockIdx.x;
    if (b >= NBATCH) return;
    const int p = b >> 1;

    // exclusive prefix of tile totals per column
    for (int c = t; c < W_IMG; c += 256) {
        float run = 0.0f;
        #pragma unroll
        for (int tt = 0; tt < NTILES; ++tt) {
            s_off[tt][c] = run;
            run += totals[((size_t)p * NTILES + tt) * W_IMG + c];
        }
    }
    __syncthreads();

    const float* S = sat + (size_t)p * H_IMG * W_IMG;

    if (t < NBOX) {
        const float* pb = pred_boxes + ((size_t)b * NBOX + t) * 4;
        const float cx = pb[0], cy = pb[1], bw = pb[2], bh = pb[3];
        const int bb0 = (int)((cx - 0.5f * bw) * 640.0f);   // vs row index
        const int bb1 = (int)((cy - 0.5f * bh) * 384.0f);   // vs col index
        const int bb2 = (int)((cx + 0.5f * bw) * 640.0f);
        const int bb3 = (int)((cy + 0.5f * bh) * 384.0f);
        const int r0 = bb0 > 0 ? bb0 : 0;
        const int r2 = bb2 < H_IMG - 1 ? bb2 : H_IMG - 1;
        const int c0 = bb1 > 0 ? bb1 : 0;
        const int c2 = bb3 < W_IMG - 1 ? bb3 : W_IMG - 1;
        float sc = 0.0f;
        if (r0 <= r2 && c0 <= c2) {
            float sum = S[(size_t)r2 * W_IMG + c2] + s_off[r2 / ROWTILE][c2];
            if (r0 > 0) sum -= S[(size_t)(r0 - 1) * W_IMG + c2] + s_off[(r0 - 1) / ROWTILE][c2];
            if (c0 > 0) sum -= S[(size_t)r2 * W_IMG + (c0 - 1)] + s_off[r2 / ROWTILE][c0 - 1];
            if (r0 > 0 && c0 > 0)
                sum += S[(size_t)(r0 - 1) * W_IMG + (c0 - 1)] + s_off[(r0 - 1) / ROWTILE][c0 - 1];
            sc = sum / (float)(H_IMG * W_IMG);
        }
        s_score[t] = sc;
    }
    __syncthreads();

    if (t == 0) {
        float b0 = -1e30f, b1 = -1e30f;
        int i0 = 0, i1 = 0;
        for (int n = 0; n < NBOX; ++n) {
            const float s = s_score[n];
            if (s > b0)      { b1 = b0; i1 = i0; b0 = s; i0 = n; }
            else if (s > b1) { b1 = s; i1 = n; }
        }
        s_idx[0] = i0;
        s_idx[1] = i1;
    }
    __syncthreads();

    s_h[0][t] = lhs[((size_t)b * NBOX + s_idx[0]) * DHID + t];
    s_h[1][t] = lhs[((size_t)b * NBOX + s_idx[1]) * DHID + t];
    __syncthreads();

    // Linear via float4 weight reads: out[o][t] = fc_b[t] + sum_d h[o][d]*W[t][d]
    const float4* wrow4 = (const float4*)(fc_w + (size_t)t * DHID);
    float acc0 = fc_b[t];
    float acc1 = acc0;
    #pragma unroll 8
    for (int d4 = 0; d4 < DHID / 4; ++d4) {
        const float4 wv = wrow4[d4];
        const int d = d4 * 4;
        acc0 = fmaf(s_h[0][d + 0], wv.x, acc0);
        acc0 = fmaf(s_h[0][d + 1], wv.y, acc0);
        acc0 = fmaf(s_h[0][d + 2], wv.z, acc0);
        acc0 = fmaf(s_h[0][d + 3], wv.w, acc0);
        acc1 = fmaf(s_h[1][d + 0], wv.x, acc1);
        acc1 = fmaf(s_h[1][d + 1], wv.y, acc1);
        acc1 = fmaf(s_h[1][d + 2], wv.z, acc1);
        acc1 = fmaf(s_h[1][d + 3], wv.w, acc1);
    }

    const size_t base = (size_t)(b & 1) * (NPAIR * 2 * DHID) + (size_t)(b >> 1) * (2 * DHID);
    out[base + t]        = acc0;
    out[base + DHID + t] = acc1;
}

extern "C" void kernel_launch(void* const* d_in, const int* in_sizes, int n_in,
                              void* d_out, int out_size, void* d_ws, size_t ws_size,
                              hipStream_t stream) {
    const float* images     = (const float*)d_in[0];
    const float* pred_boxes = (const float*)d_in[2];
    const float* lhs        = (const float*)d_in[3];
    const float* fc_w       = (const float*)d_in[4];
    const float* fc_b       = (const float*)d_in[5];
    float* out              = (float*)d_out;

    float* sat    = (float*)d_ws;                                   // 3.93 MB
    float* totals = sat + (size_t)NPAIR * H_IMG * W_IMG;            // 160 KB

    void* args[] = {(void*)&images, (void*)&sat, (void*)&totals, (void*)&pred_boxes,
                    (void*)&lhs, (void*)&fc_w, (void*)&fc_b, (void*)&out};
    hipLaunchCooperativeKernel((const void*)k_fused, dim3(NBLOCKS), dim3(256),
                               args, 0, stream);
}

// Round 4
// 100.759 us; speedup vs baseline: 1.8264x; 1.8264x over previous
//
#include <hip/hip_runtime.h>

#define H_IMG 384
#define W_IMG 640
#define NPAIR 4
#define NBATCH 8
#define NBOX 100
#define DHID 256
#define ROWTILE 24
#define NTILES (H_IMG / ROWTILE)   // 16

// ---------------------------------------------------------------------------
// Kernel A: one block per (pair, row-tile): 4*16 = 64 blocks x 256 threads.
//  Step 1: for the tile's 24 rows: diff = |sum_c img[2p+1] - sum_c img[2p]|,
//          fp32 inclusive row scan (float2 lanes, 5 chunks), stash in LDS.
//  Step 2: column scan over the 24 LDS rows, write tile-local SAT to global
//          + per-column tile totals (transposed layout [p][c][tile]).
// ---------------------------------------------------------------------------
__global__ __launch_bounds__(256) void k_sat_tile(const float* __restrict__ images,
                                                  float* __restrict__ sat,
                                                  float* __restrict__ totals_t) {
    __shared__ float buf[ROWTILE][W_IMG];   // 60 KB

    const int p    = blockIdx.x >> 4;        // pair
    const int tile = blockIdx.x & 15;        // row tile
    const int lane = threadIdx.x & 63;
    const int wv   = threadIdx.x >> 6;       // wave 0..3
    const int r_lo = tile * ROWTILE;

    const size_t chw = (size_t)H_IMG * W_IMG;

    // ---- Step 1: diff + row scan, 6 rows per wave ----
    for (int rr = wv; rr < ROWTILE; rr += 4) {
        const int h = r_lo + rr;
        const float2* i0 = (const float2*)(images + ((size_t)(2 * p)     * 3 * H_IMG + h) * W_IMG);
        const float2* i1 = (const float2*)(images + ((size_t)(2 * p + 1) * 3 * H_IMG + h) * W_IMG);
        const size_t chw2 = chw / 2;

        float carry = 0.0f;
        #pragma unroll
        for (int k = 0; k < 5; ++k) {
            const int e = k * 64 + lane;     // float2 index within row
            float2 a0 = i0[e], b0 = i0[e + chw2], c0 = i0[e + 2 * chw2];
            float2 a1 = i1[e], b1 = i1[e + chw2], c1 = i1[e + 2 * chw2];
            float dx = fabsf(((a1.x + b1.x) + c1.x) - ((a0.x + b0.x) + c0.x));
            float dy = fabsf(((a1.y + b1.y) + c1.y) - ((a0.y + b0.y) + c0.y));
            float s = dx + dy;
            // inclusive wave scan of pair sums
            #pragma unroll
            for (int off = 1; off < 64; off <<= 1) {
                float u = __shfl_up(s, off, 64);
                if (lane >= off) s += u;
            }
            const float excl = s - (dx + dy);
            buf[rr][2 * e]     = carry + excl + dx;
            buf[rr][2 * e + 1] = carry + excl + dx + dy;
            carry += __shfl(s, 63, 64);
        }
    }
    __syncthreads();

    // ---- Step 2: column scan within tile ----
    const int t = threadIdx.x;
    #pragma unroll
    for (int sub = 0; sub < 3; ++sub) {
        const int c = sub * 256 + t;
        if (c < W_IMG) {
            float run = 0.0f;
            float* gcol = sat + ((size_t)p * H_IMG + r_lo) * W_IMG + c;
            #pragma unroll
            for (int i = 0; i < ROWTILE; ++i) {
                run += buf[i][c];
                gcol[(size_t)i * W_IMG] = run;
            }
            totals_t[((size_t)p * W_IMG + c) * NTILES + tile] = run;
        }
    }
}

// ---------------------------------------------------------------------------
// Kernel B: one block per batch (8 blocks x 256).
//  Phase A: per-column exclusive scan of 16 contiguous tile totals -> LDS.
//  Phase B: box scores via SAT(r,c) = local[r][c] + s_off[r/24][c] (O(1)).
//  Phase C: top-2 (jax.lax.top_k tie-break: lower index first).
//  Phase D: gather hidden states + fused Linear + interleaved output.
// ---------------------------------------------------------------------------
__global__ __launch_bounds__(256) void k_score_topk_fc(
        const float* __restrict__ sat,
        const float* __restrict__ totals_t,
        const float* __restrict__ pred_boxes,
        const float* __restrict__ lhs,
        const float* __restrict__ fc_w,
        const float* __restrict__ fc_b,
        float* __restrict__ out) {
    const int b = blockIdx.x;
    const int t = threadIdx.x;
    const int p = b >> 1;

    __shared__ float s_off[NTILES][W_IMG];   // 40 KB
    __shared__ float s_score[NBOX];
    __shared__ int   s_idx[2];
    __shared__ float s_h[2][DHID];

    // Phase A: contiguous 16-float read per column, exclusive scan in regs
    for (int c = t; c < W_IMG; c += 256) {
        const float4* tp = (const float4*)(totals_t + ((size_t)p * W_IMG + c) * NTILES);
        float4 v0 = tp[0], v1 = tp[1], v2 = tp[2], v3 = tp[3];
        float tv[NTILES] = {v0.x, v0.y, v0.z, v0.w, v1.x, v1.y, v1.z, v1.w,
                            v2.x, v2.y, v2.z, v2.w, v3.x, v3.y, v3.z, v3.w};
        float run = 0.0f;
        #pragma unroll
        for (int tt = 0; tt < NTILES; ++tt) {
            s_off[tt][c] = run;
            run += tv[tt];
        }
    }
    __syncthreads();

    const float* S = sat + (size_t)p * H_IMG * W_IMG;

    // Phase B: scores
    if (t < NBOX) {
        const float* pb = pred_boxes + ((size_t)b * NBOX + t) * 4;
        const float cx = pb[0], cy = pb[1], bw = pb[2], bh = pb[3];
        const int bb0 = (int)((cx - 0.5f * bw) * 640.0f);   // vs row index
        const int bb1 = (int)((cy - 0.5f * bh) * 384.0f);   // vs col index
        const int bb2 = (int)((cx + 0.5f * bw) * 640.0f);
        const int bb3 = (int)((cy + 0.5f * bh) * 384.0f);
        const int r0 = bb0 > 0 ? bb0 : 0;
        const int r2 = bb2 < H_IMG - 1 ? bb2 : H_IMG - 1;
        const int c0 = bb1 > 0 ? bb1 : 0;
        const int c2 = bb3 < W_IMG - 1 ? bb3 : W_IMG - 1;
        float sc = 0.0f;
        if (r0 <= r2 && c0 <= c2) {
            float sum = S[(size_t)r2 * W_IMG + c2] + s_off[r2 / ROWTILE][c2];
            if (r0 > 0) sum -= S[(size_t)(r0 - 1) * W_IMG + c2] + s_off[(r0 - 1) / ROWTILE][c2];
            if (c0 > 0) sum -= S[(size_t)r2 * W_IMG + (c0 - 1)] + s_off[r2 / ROWTILE][c0 - 1];
            if (r0 > 0 && c0 > 0)
                sum += S[(size_t)(r0 - 1) * W_IMG + (c0 - 1)] + s_off[(r0 - 1) / ROWTILE][c0 - 1];
            sc = sum / (float)(H_IMG * W_IMG);
        }
        s_score[t] = sc;
    }
    __syncthreads();

    // Phase C: top-2
    if (t == 0) {
        float b0 = -1e30f, b1 = -1e30f;
        int i0 = 0, i1 = 0;
        for (int n = 0; n < NBOX; ++n) {
            const float s = s_score[n];
            if (s > b0)      { b1 = b0; i1 = i0; b0 = s; i0 = n; }
            else if (s > b1) { b1 = s; i1 = n; }
        }
        s_idx[0] = i0;
        s_idx[1] = i1;
    }
    __syncthreads();

    // Phase D: gather + Linear
    s_h[0][t] = lhs[((size_t)b * NBOX + s_idx[0]) * DHID + t];
    s_h[1][t] = lhs[((size_t)b * NBOX + s_idx[1]) * DHID + t];
    __syncthreads();

    const float4* wrow4 = (const float4*)(fc_w + (size_t)t * DHID);
    float acc0 = fc_b[t];
    float acc1 = acc0;
    #pragma unroll 8
    for (int d4 = 0; d4 < DHID / 4; ++d4) {
        const float4 wv = wrow4[d4];
        const int d = d4 * 4;
        acc0 = fmaf(s_h[0][d + 0], wv.x, acc0);
        acc0 = fmaf(s_h[0][d + 1], wv.y, acc0);
        acc0 = fmaf(s_h[0][d + 2], wv.z, acc0);
        acc0 = fmaf(s_h[0][d + 3], wv.w, acc0);
        acc1 = fmaf(s_h[1][d + 0], wv.x, acc1);
        acc1 = fmaf(s_h[1][d + 1], wv.y, acc1);
        acc1 = fmaf(s_h[1][d + 2], wv.z, acc1);
        acc1 = fmaf(s_h[1][d + 3], wv.w, acc1);
    }

    const size_t base = (size_t)(b & 1) * (NPAIR * 2 * DHID) + (size_t)(b >> 1) * (2 * DHID);
    out[base + t]        = acc0;
    out[base + DHID + t] = acc1;
}

extern "C" void kernel_launch(void* const* d_in, const int* in_sizes, int n_in,
                              void* d_out, int out_size, void* d_ws, size_t ws_size,
                              hipStream_t stream) {
    const float* images     = (const float*)d_in[0];
    const float* pred_boxes = (const float*)d_in[2];
    const float* lhs        = (const float*)d_in[3];
    const float* fc_w       = (const float*)d_in[4];
    const float* fc_b       = (const float*)d_in[5];
    float* out              = (float*)d_out;

    float* sat      = (float*)d_ws;                              // 3.93 MB
    float* totals_t = sat + (size_t)NPAIR * H_IMG * W_IMG;       // 160 KB, 64B-aligned

    hipLaunchKernelGGL(k_sat_tile, dim3(NPAIR * NTILES), dim3(256), 0, stream,
                       images, sat, totals_t);
    hipLaunchKernelGGL(k_score_topk_fc, dim3(NBATCH), dim3(256), 0, stream,
                       sat, totals_t, pred_boxes, lhs, fc_w, fc_b, out);
}